// Round 7
// baseline (287.859 us; speedup 1.0000x reference)
//
#include <hip/hip_runtime.h>

#define ROW_LEN 128
#define NPAIR (129 * 129)   // (seq, uniq) pairs, each in [0,128]
#define TBL 1024            // tag-table words per wave (4 KB)

// Kernel A: precompute MLP(feats(seq,uniq)) for all 16641 pairs -> table[p][32].
__global__ __launch_bounds__(256) void mlp_table_kernel(
    const float* __restrict__ W1, const float* __restrict__ b1,
    const float* __restrict__ W2, const float* __restrict__ b2,
    float* __restrict__ table)
{
    const int tid = blockIdx.x * 256 + threadIdx.x;
    if (tid >= NPAIR * 32) return;
    const int p = tid >> 5;
    const int j = tid & 31;
    const int seq  = p / 129;
    const int uniq = p % 129;
    const float f0 = (float)seq  * (1.0f / 128.0f);
    const float f1 = (float)uniq * (1.0f / 128.0f);
    const float f2 = (seq > 0) ? ((float)uniq / (float)seq) : 0.0f;

    float acc = b2[j];
    #pragma unroll
    for (int jj = 0; jj < 32; ++jj) {
        float h = b1[jj];                 // lane-uniform -> scalar loads
        h = fmaf(f0, W1[jj],      h);
        h = fmaf(f1, W1[32 + jj], h);
        h = fmaf(f2, W1[64 + jj], h);
        h = fmaxf(h, 0.0f);
        acc = fmaf(h, W2[jj * 32 + j], acc);
    }
    table[tid] = fmaxf(acc, 0.0f);
}

// Kernel B: one row per wave. Last-writer-wins tag table — NO atomics, NO
// table initialization. Masked tokens plain-write a unique position id
// (lane for .x, 64+lane for .y) to tb[h(tok)], then read back: the word's
// last writer sees its own id -> "winner". uniq = #winners + verify of the
// rare candidates (same-word collisions, E~2/row) via readlane+ballot, which
// counts each distinct unclaimed token exactly once. Correct for any data
// and any HW same-address write order. No init needed: every reader wrote
// the word first, so stale/poison data can never be observed.
__global__ __launch_bounds__(256) void rows_kernel(
    const int* __restrict__ ids, const int* __restrict__ amask,
    const float* __restrict__ table, float* __restrict__ out, int B)
{
    __shared__ unsigned tb[4][TBL];    // 4 KB tag table per wave, never zeroed

    const int wave = threadIdx.x >> 6;
    const int lane = threadIdx.x & 63;
    const long row = (long)blockIdx.x * 4 + wave;
    if (row >= B) return;              // B % 4 == 0; cosmetic

    // coalesced loads: lane i covers row positions [2i, 2i+2)
    const long v = row * 64 + lane;
    const int2 id2 = ((const int2*)ids)[v];
    const int2 mk2 = ((const int2*)amask)[v];

    volatile unsigned* t = tb[wave];   // volatile: keep write->read, defeat S2L fwd

    const bool mx = (mk2.x != 0);
    const bool my = (mk2.y != 0);
    const unsigned hx = ((unsigned)id2.x) & (TBL - 1);
    const unsigned hy = ((unsigned)id2.y) & (TBL - 1);

    // phase 1: plain scattered writes of unique position ids (masked only)
    if (mx) t[hx] = (unsigned)lane;
    if (my) t[hy] = (unsigned)(64 + lane);

    // phase 2: scattered read-back (same-wave DS ops execute in order)
    const unsigned r0 = t[hx];
    const unsigned r1 = t[hy];

    const bool win0 = mx && (r0 == (unsigned)lane);
    const bool win1 = my && (r1 == (unsigned)(64 + lane));

    const int seq = __popcll(__ballot(mx)) + __popcll(__ballot(my));
    int uniq = __popcll(__ballot(win0)) + __popcll(__ballot(win1));

    // verify loop over candidates (masked non-winners); wave-uniform, E~2 iters
    unsigned long long p0 = __ballot(mx && !win0);
    unsigned long long p1 = __ballot(my && !win1);
    while (p0 | p1) {
        int T;
        if (p0) {
            const int l = __ffsll((long long)p0) - 1;
            T = __builtin_amdgcn_readlane(id2.x, l);
        } else {
            const int l = __ffsll((long long)p1) - 1;
            T = __builtin_amdgcn_readlane(id2.y, l);
        }
        const unsigned long long ex = __ballot(mx && (id2.x == T));
        const unsigned long long ey = __ballot(my && (id2.y == T));
        const unsigned long long w  = __ballot((win0 && (id2.x == T)) ||
                                               (win1 && (id2.y == T)));
        uniq += (w == 0ull);           // token truly unclaimed: count once
        p0 &= ~ex;                     // clear all occurrences of T
        p1 &= ~ey;
    }

    // epilogue: 128B L2-hot table gather, contiguous 128B store
    const int p = seq * 129 + uniq;
    if (lane < 32) out[row * 32 + lane] = table[p * 32 + lane];
}

extern "C" void kernel_launch(void* const* d_in, const int* in_sizes, int n_in,
                              void* d_out, int out_size, void* d_ws, size_t ws_size,
                              hipStream_t stream) {
    const int*   ids   = (const int*)d_in[0];
    const int*   amask = (const int*)d_in[1];
    const float* W1    = (const float*)d_in[2];
    const float* b1    = (const float*)d_in[3];
    const float* W2    = (const float*)d_in[4];
    const float* b2    = (const float*)d_in[5];
    float* out   = (float*)d_out;
    float* table = (float*)d_ws;       // NPAIR*32*4 = 2.13 MB of ws

    const int B = in_sizes[0] / ROW_LEN;              // 262144

    const int tblThreads = NPAIR * 32;
    mlp_table_kernel<<<(tblThreads + 255) / 256, 256, 0, stream>>>(W1, b1, W2, b2, table);

    // 1 row per wave, 4 waves per block
    rows_kernel<<<(B + 3) / 4, 256, 0, stream>>>(ids, amask, table, out, B);
}